// Round 1
// baseline (123.669 us; speedup 1.0000x reference)
//
#include <hip/hip_runtime.h>

// BottomPool: out[b,c,h,w] = max_{h'<=h} x[b,c,h',w]
// x: (16, 256, 128, 128) fp32, contiguous, W innermost.
// One thread per float4-group of a (b,c,:,w) column; sequential scan over H
// with running max in registers. Memory-bound: 1 read + 1 write per element.

#define H_DIM 128
#define W4_DIM 32  // W=128 floats / 4 per float4

__global__ __launch_bounds__(256) void bottom_pool_kernel(
    const float4* __restrict__ x, float4* __restrict__ out, int ncols4) {
    int idx = blockIdx.x * blockDim.x + threadIdx.x;
    if (idx >= ncols4) return;

    int w4 = idx & (W4_DIM - 1);   // position within row, float4 units
    int bc = idx >> 5;             // b*C + c  (idx / 32)
    size_t base = (size_t)bc * (H_DIM * W4_DIM) + w4;

    float4 m = x[base];
    out[base] = m;

#pragma unroll 4
    for (int h = 1; h < H_DIM; ++h) {
        size_t off = base + (size_t)h * W4_DIM;
        float4 v = x[off];
        m.x = fmaxf(m.x, v.x);
        m.y = fmaxf(m.y, v.y);
        m.z = fmaxf(m.z, v.z);
        m.w = fmaxf(m.w, v.w);
        out[off] = m;
    }
}

extern "C" void kernel_launch(void* const* d_in, const int* in_sizes, int n_in,
                              void* d_out, int out_size, void* d_ws, size_t ws_size,
                              hipStream_t stream) {
    const float4* x = (const float4*)d_in[0];
    float4* out = (float4*)d_out;

    // total float4 column-groups: B*C*W4 = out_size / (H*4)
    int ncols4 = out_size / (H_DIM * 4);

    int block = 256;
    int grid = (ncols4 + block - 1) / block;
    bottom_pool_kernel<<<grid, block, 0, stream>>>(x, out, ncols4);
}

// Round 2
// 105.081 us; speedup vs baseline: 1.1769x; 1.1769x over previous
//
#include <hip/hip_runtime.h>
#include <cfloat>

// BottomPool: out[b,c,h,w] = max_{h'<=h} x[b,c,h',w]
// x: (16, 256, 128, 128) fp32 contiguous, W innermost.
//
// Segmented scan: one block per (b,c) image. 256 threads = 32 float4-columns
// x 8 H-segments of 16 rows. Each thread loads its 16 rows (all loads
// independent -> 16 KB/wave in flight), computes a local register cummax,
// publishes its segment max to LDS, takes the exclusive prefix-max of the
// preceding segments, applies it, and stores. 1 read + 1 write per element.

#define H_DIM 128
#define W4_DIM 32   // W=128 floats / 4
#define SEG 16      // rows per thread
#define NSEG 8      // H_DIM / SEG

__device__ __forceinline__ float4 f4max(float4 a, float4 b) {
    return make_float4(fmaxf(a.x, b.x), fmaxf(a.y, b.y),
                       fmaxf(a.z, b.z), fmaxf(a.w, b.w));
}

__global__ __launch_bounds__(256) void bottom_pool_kernel(
    const float4* __restrict__ x, float4* __restrict__ out) {
    __shared__ float4 smax[NSEG][W4_DIM];

    int tid = threadIdx.x;
    int col = tid & (W4_DIM - 1);  // float4 column within the row
    int s   = tid >> 5;            // segment index 0..7

    // base of this thread's first row: image blockIdx.x, row s*SEG, col
    size_t base = (size_t)blockIdx.x * (H_DIM * W4_DIM)
                + (size_t)(s * SEG) * W4_DIM + col;

    // 1) load 16 rows — all independent, coalesced (lanes 0..31 contiguous)
    float4 v[SEG];
#pragma unroll
    for (int j = 0; j < SEG; ++j) v[j] = x[base + (size_t)j * W4_DIM];

    // 2) local inclusive cummax within the segment
#pragma unroll
    for (int j = 1; j < SEG; ++j) v[j] = f4max(v[j], v[j - 1]);

    // 3) publish segment max, exclusive prefix-max over earlier segments
    smax[s][col] = v[SEG - 1];
    __syncthreads();

    float4 p = make_float4(-FLT_MAX, -FLT_MAX, -FLT_MAX, -FLT_MAX);
    for (int t = 0; t < s; ++t) p = f4max(p, smax[t][col]);

    // 4) apply prefix and store (coalesced, fire-and-forget)
#pragma unroll
    for (int j = 0; j < SEG; ++j)
        out[base + (size_t)j * W4_DIM] = f4max(p, v[j]);
}

extern "C" void kernel_launch(void* const* d_in, const int* in_sizes, int n_in,
                              void* d_out, int out_size, void* d_ws, size_t ws_size,
                              hipStream_t stream) {
    const float4* x = (const float4*)d_in[0];
    float4* out = (float4*)d_out;

    int n_images = out_size / (H_DIM * W4_DIM * 4);  // B*C = 4096
    bottom_pool_kernel<<<n_images, 256, 0, stream>>>(x, out);
}

// Round 3
// 91.497 us; speedup vs baseline: 1.3516x; 1.1485x over previous
//
#include <hip/hip_runtime.h>
#include <cfloat>

// BottomPool: out[b,c,h,w] = max_{h'<=h} x[b,c,h',w]
// x: (16, 256, 128, 128) fp32 contiguous, W innermost.
//
// Segmented scan, one block per (b,c) image: 256 threads = 32 float4-columns
// x 8 H-segments of 16 rows. 16 independent nontemporal loads per thread,
// register cummax, LDS exchange of segment maxima, exclusive prefix-max,
// apply + nontemporal store. Traffic = exactly 1 read + 1 write per element;
// nt hints keep the two 256 MiB streams from thrashing L2/LLC.

#define H_DIM 128
#define W4_DIM 32   // W=128 floats / 4
#define SEG 16      // rows per thread
#define NSEG 8      // H_DIM / SEG

typedef float f4 __attribute__((ext_vector_type(4)));

__device__ __forceinline__ f4 f4max(f4 a, f4 b) {
    f4 r;
    r.x = fmaxf(a.x, b.x);
    r.y = fmaxf(a.y, b.y);
    r.z = fmaxf(a.z, b.z);
    r.w = fmaxf(a.w, b.w);
    return r;
}

__global__ __launch_bounds__(256) void bottom_pool_kernel(
    const f4* __restrict__ x, f4* __restrict__ out) {
    __shared__ f4 smax[NSEG][W4_DIM];

    int tid = threadIdx.x;
    int col = tid & (W4_DIM - 1);  // float4 column within the row
    int s   = tid >> 5;            // segment index 0..7

    // 32-bit offsets: max index = 4096 images * 4096 f4 = 2^24, fits easily.
    int base = blockIdx.x * (H_DIM * W4_DIM) + s * (SEG * W4_DIM) + col;

    // 1) 16 independent, coalesced, nontemporal loads
    f4 v[SEG];
#pragma unroll
    for (int j = 0; j < SEG; ++j)
        v[j] = __builtin_nontemporal_load(&x[base + j * W4_DIM]);

    // 2) local inclusive cummax within the segment
#pragma unroll
    for (int j = 1; j < SEG; ++j) v[j] = f4max(v[j], v[j - 1]);

    // 3) publish segment max; exclusive prefix-max over earlier segments
    smax[s][col] = v[SEG - 1];
    __syncthreads();

    f4 p = {-FLT_MAX, -FLT_MAX, -FLT_MAX, -FLT_MAX};
    for (int t = 0; t < s; ++t) p = f4max(p, smax[t][col]);

    // 4) apply prefix, nontemporal store (fire-and-forget)
#pragma unroll
    for (int j = 0; j < SEG; ++j)
        __builtin_nontemporal_store(f4max(p, v[j]), &out[base + j * W4_DIM]);
}

extern "C" void kernel_launch(void* const* d_in, const int* in_sizes, int n_in,
                              void* d_out, int out_size, void* d_ws, size_t ws_size,
                              hipStream_t stream) {
    const f4* x = (const f4*)d_in[0];
    f4* out = (f4*)d_out;

    int n_images = out_size / (H_DIM * W4_DIM * 4);  // B*C = 4096
    bottom_pool_kernel<<<n_images, 256, 0, stream>>>(x, out);
}